// Round 6
// baseline (436.137 us; speedup 1.0000x reference)
//
#include <hip/hip_runtime.h>

// Adaptive softmax NLL — merged single-launch bf16-MFMA GEMM, BK=32,
// 4 blocks/CU occupancy, chunk-column-major LDS (conflict-free, no XOR).
//
// Padded reordered weight (bf16) in ws (128-row chunks):
//   head : rows [0,5120)      = weight[0:5000] ++ cluster_weight ++ pad (40 chunks)
//   tail1: rows [5120,15232)  = weight[5000:15000]  ++ pad (79 chunks)
//   tail2: rows [15232,30336) = weight[15000:30000] ++ pad (118 chunks)
//   tail3: rows [30336,50688) = weight[30000:50257] ++ pad (159 chunks)
// Pad rows: w=0, bias=-1e30 (vanish in exp-weighted LSE merges).

#define D 512
#define NROWS_PAD 50688
#define NTOK 4096
#define NTOKP 4736
#define HEAD_CHUNKS 40
#define TAILP_STRIDE 160

typedef __attribute__((ext_vector_type(8))) short short8;
typedef __attribute__((ext_vector_type(4))) float f32x4;

__device__ __forceinline__ unsigned short f2bf(float f) {
    unsigned int u = __float_as_uint(f);
    u += 0x7FFFu + ((u >> 16) & 1u);
    return (unsigned short)(u >> 16);
}

__device__ __forceinline__ void gload_lds16(const void* g, void* l) {
    __builtin_amdgcn_global_load_lds(
        (const __attribute__((address_space(1))) unsigned int*)g,
        (__attribute__((address_space(3))) unsigned int*)l, 16, 0, 0);
}

// ---------------- bucket tokens by cluster (deterministic counting sort) ----------------
__global__ __launch_bounds__(256) void k_bucket(
    const int* __restrict__ target, int* __restrict__ perm,
    int* __restrict__ inv, int* __restrict__ meta)
{
    __shared__ int cnt[256][4];
    __shared__ int basesh[256][4];
    __shared__ int sTot[4], sOff[4];
    const int th = threadIdx.x;
    for (int p = th; p < NTOKP; p += 256) perm[p] = -1;
    int lc[4] = {0, 0, 0, 0};
    #pragma unroll
    for (int i = 0; i < 16; ++i) {
        int tg = target[th * 16 + i];
        int c = (tg >= 5000) + (tg >= 15000) + (tg >= 30000);
        lc[c]++;
    }
    #pragma unroll
    for (int c = 0; c < 4; ++c) cnt[th][c] = lc[c];
    __syncthreads();
    if (th < 4) {
        int tot = 0;
        for (int i = 0; i < 256; ++i) tot += cnt[i][th];
        sTot[th] = tot;
    }
    __syncthreads();
    if (th == 0) {
        int b = 0;
        for (int c = 1; c < 4; ++c) { sOff[c] = b; b += ((sTot[c] + 127) >> 7) << 7; }
        meta[0] = sTot[1]; meta[1] = sTot[2]; meta[2] = sTot[3];
        meta[3] = sOff[1]; meta[4] = sOff[2]; meta[5] = sOff[3];
        meta[6] = (sTot[1] + 127) >> 7;
        meta[7] = (sTot[2] + 127) >> 7;
        meta[8] = (sTot[3] + 127) >> 7;
    }
    __syncthreads();
    if (th >= 1 && th < 4) {
        int run = sOff[th];
        for (int i = 0; i < 256; ++i) { basesh[i][th] = run; run += cnt[i][th]; }
    }
    __syncthreads();
    int run[4];
    #pragma unroll
    for (int c = 1; c < 4; ++c) run[c] = basesh[th][c];
    for (int i = 0; i < 16; ++i) {
        int t = th * 16 + i;
        int tg = target[t];
        int c = (tg >= 5000) + (tg >= 15000) + (tg >= 30000);
        if (c > 0) { int pos = run[c]++; perm[pos] = t; inv[t] = pos; }
        else inv[t] = -1;
    }
}

// ---------------- convert / reorder / pad / gather ----------------
__global__ __launch_bounds__(128) void k_convert(
    const float* __restrict__ weight, const float* __restrict__ bias,
    const float* __restrict__ cweight, const float* __restrict__ cbias,
    const float* __restrict__ hidden, const int* __restrict__ perm,
    unsigned short* __restrict__ wsW, float* __restrict__ wsB,
    unsigned short* __restrict__ wsH, unsigned short* __restrict__ wsHc)
{
    const int r = blockIdx.x;
    const int i = threadIdx.x;   // 0..127, one float4 each
    if (r < NROWS_PAD) {
        const int pstart[4] = {0, 5120, 15232, 30336};
        const int plen[4]   = {5003, 10000, 15000, 20257};
        const int psrc[4]   = {0, 5000, 15000, 30000};
        int p = (r < 5120) ? 0 : (r < 15232) ? 1 : (r < 30336) ? 2 : 3;
        int o = r - pstart[p];
        const float* src = nullptr;
        float b = -1e30f;
        if (o < plen[p]) {
            if (p == 0 && o >= 5000) { src = cweight + (size_t)(o - 5000) * D; b = cbias[o - 5000]; }
            else { int sr = psrc[p] + o; src = weight + (size_t)sr * D; b = bias[sr]; }
        }
        float4 v = src ? ((const float4*)src)[i] : make_float4(0.f, 0.f, 0.f, 0.f);
        ushort4 u;
        u.x = f2bf(v.x); u.y = f2bf(v.y); u.z = f2bf(v.z); u.w = f2bf(v.w);
        ((ushort4*)(wsW + (size_t)r * D))[i] = u;
        if (i == 0) wsB[r] = b;
    } else if (r < NROWS_PAD + NTOK) {
        int hr = r - NROWS_PAD;
        float4 v = ((const float4*)(hidden + (size_t)hr * D))[i];
        ushort4 u;
        u.x = f2bf(v.x); u.y = f2bf(v.y); u.z = f2bf(v.z); u.w = f2bf(v.w);
        ((ushort4*)(wsH + (size_t)hr * D))[i] = u;
    } else {
        int p = r - NROWS_PAD - NTOK;       // compacted position
        int tok = perm[p];
        float4 v = (tok >= 0) ? ((const float4*)(hidden + (size_t)tok * D))[i]
                              : make_float4(0.f, 0.f, 0.f, 0.f);
        ushort4 u;
        u.x = f2bf(v.x); u.y = f2bf(v.y); u.z = f2bf(v.z); u.w = f2bf(v.w);
        ((ushort4*)(wsHc + (size_t)p * D))[i] = u;
    }
}

// ---------------- exact fp32 dots for the two needed logits ----------------
__global__ __launch_bounds__(256) void k_stash(
    const float* __restrict__ hidden, const int* __restrict__ target,
    const float* __restrict__ weight, const float* __restrict__ bias,
    const float* __restrict__ cweight, const float* __restrict__ cbias,
    float2* __restrict__ stash)
{
    const int wave = threadIdx.x >> 6, lane = threadIdx.x & 63;
    const int t = blockIdx.x * 4 + wave;
    const int tg = target[t];
    const int ci = (tg >= 5000) + (tg >= 15000) + (tg >= 30000);
    const float4* h = (const float4*)(hidden + (size_t)t * D);
    const float4* w = (const float4*)(weight + (size_t)tg * D);
    const float4* c = (const float4*)(cweight + (size_t)(ci ? 3 - ci : 0) * D);
    float dw = 0.f, dc = 0.f;
    #pragma unroll
    for (int u = 0; u < 2; ++u) {
        float4 hh = h[lane * 2 + u];
        float4 ww = w[lane * 2 + u];
        float4 cc = c[lane * 2 + u];
        dw += hh.x * ww.x + hh.y * ww.y + hh.z * ww.z + hh.w * ww.w;
        dc += hh.x * cc.x + hh.y * cc.y + hh.z * cc.z + hh.w * cc.w;
    }
    #pragma unroll
    for (int off = 1; off < 64; off <<= 1) {
        dw += __shfl_xor(dw, off, 64);
        dc += __shfl_xor(dc, off, 64);
    }
    if (lane == 0) {
        float head = ci ? dc + cbias[3 - ci] : dw + bias[tg];
        float tail = ci ? dw + bias[tg]      : 0.f;
        stash[t] = make_float2(head, tail);
    }
}

// ---------------- merged 128x128 GEMM (BK=32) + per-chunk LSE partial ----------------
// One launch over all partitions, chunk-major order + XCD-contiguous remap.
// 256 threads = 4 waves (2Mx2N). LDS per K-step: chunk-column-major slots
// (slot = c*128 + r, 16B each) -> frag reads are contiguous 16B runs, no conflicts.
__global__ __launch_bounds__(256, 4) void k_gemm_all(
    const unsigned short* __restrict__ wsW, const float* __restrict__ wsB,
    const unsigned short* __restrict__ wsH, const unsigned short* __restrict__ wsHc,
    float2* __restrict__ headP, float2* __restrict__ tailP,
    const int* __restrict__ meta)
{
    // nwg = 12672 = 8 * 1584; give each XCD a contiguous chunk-major range
    const int work = (blockIdx.x & 7) * 1584 + (blockIdx.x >> 3);
    int p, chunk, tau;
    if (work < 1280)      { p = 0; chunk = work >> 5;          tau = work & 31; }
    else if (work < 3808) { p = 1; chunk = (work - 1280) >> 5; tau = (work - 1280) & 31; }
    else if (work < 7584) { p = 2; chunk = (work - 3808) >> 5; tau = (work - 3808) & 31; }
    else                  { p = 3; chunk = (work - 7584) >> 5; tau = (work - 7584) & 31; }

    int tokBase = 0;
    const unsigned short* H = wsH;
    if (p > 0) {
        if (tau >= meta[5 + p]) return;   // data-dependent token-tile count
        tokBase = meta[2 + p];
        H = wsHc;
    }
    const int pstart_[4] = {0, 5120, 15232, 30336};
    const int rowBase = pstart_[p] + chunk * 128;

    const int tid = threadIdx.x;
    const int w = tid >> 6, lane = tid & 63;
    const int wm = w >> 1, wn = w & 1;
    const int lm = lane & 15, kg = lane >> 4;

    __shared__ unsigned short ldsA[2][512 * 8];   // 512 slots x 16B
    __shared__ unsigned short ldsB[2][512 * 8];
    __shared__ float2 sred[2][128];

    const unsigned short* Wb = wsW + (size_t)rowBase * D;
    const unsigned short* Hb = H + (size_t)(tokBase + tau * 128) * D;

    auto STAGE = [&](int buf, int kt) {
        #pragma unroll
        for (int j = 0; j < 2; ++j) {
            int e = tid + j * 256;            // LDS slot (16B units)
            int r = e & 127, c = e >> 7;      // col-major-in-chunks layout
            size_t go = (size_t)r * D + (size_t)kt * 32 + c * 8;
            gload_lds16(Wb + go, &ldsA[buf][e * 8]);
            gload_lds16(Hb + go, &ldsB[buf][e * 8]);
        }
    };

    f32x4 acc[4][4];
    #pragma unroll
    for (int m = 0; m < 4; ++m)
        #pragma unroll
        for (int n = 0; n < 4; ++n) acc[m][n] = (f32x4){0.f, 0.f, 0.f, 0.f};

    // frag base slots: slot = kg*128 + row
    const int aoff = (kg * 128 + wm * 64 + lm) * 8;   // ushort index
    const int boff = (kg * 128 + wn * 64 + lm) * 8;

    STAGE(0, 0);
    __syncthreads();

    int buf = 0;
    for (int s = 0; s < 16; ++s) {
        if (s < 15) STAGE(buf ^ 1, s + 1);
        short8 af[4], bfr[4];
        #pragma unroll
        for (int m = 0; m < 4; ++m)
            af[m] = *(const short8*)&ldsA[buf][aoff + m * 16 * 8];
        #pragma unroll
        for (int n = 0; n < 4; ++n)
            bfr[n] = *(const short8*)&ldsB[buf][boff + n * 16 * 8];
        #pragma unroll
        for (int m = 0; m < 4; ++m)
            #pragma unroll
            for (int n = 0; n < 4; ++n)
                acc[m][n] = __builtin_amdgcn_mfma_f32_16x16x32_bf16(af[m], bfr[n], acc[m][n], 0, 0, 0);
        __syncthreads();
        buf ^= 1;
    }

    // epilogue: bias + per-token LSE over this chunk's 128 rows
    f32x4 bb[4];
    #pragma unroll
    for (int m = 0; m < 4; ++m)
        bb[m] = *(const f32x4*)(wsB + rowBase + wm * 64 + m * 16 + kg * 4);

    #pragma unroll
    for (int n = 0; n < 4; ++n) {
        float mval = -1e30f;
        #pragma unroll
        for (int m = 0; m < 4; ++m)
            #pragma unroll
            for (int j = 0; j < 4; ++j) {
                acc[m][n][j] += bb[m][j];
                mval = fmaxf(mval, acc[m][n][j]);
            }
        float sval = 0.f;
        #pragma unroll
        for (int m = 0; m < 4; ++m)
            #pragma unroll
            for (int j = 0; j < 4; ++j)
                sval += __expf(acc[m][n][j] - mval);
        #pragma unroll
        for (int off = 16; off < 64; off <<= 1) {
            float m2 = __shfl_xor(mval, off, 64);
            float s2 = __shfl_xor(sval, off, 64);
            float M = fmaxf(mval, m2);
            sval = sval * __expf(mval - M) + s2 * __expf(m2 - M);
            mval = M;
        }
        if (lane < 16)
            sred[wm][wn * 64 + n * 16 + lane] = make_float2(mval, sval);
    }
    __syncthreads();
    if (tid < 128) {
        float2 p0 = sred[0][tid], p1 = sred[1][tid];
        float M = fmaxf(p0.x, p1.x);
        float S = p0.y * __expf(p0.x - M) + p1.y * __expf(p1.x - M);
        if (p == 0)
            headP[(size_t)(tau * 128 + tid) * HEAD_CHUNKS + chunk] = make_float2(M, S);
        else
            tailP[(size_t)(tokBase + tau * 128 + tid) * TAILP_STRIDE + chunk] = make_float2(M, S);
    }
}

// ---------------- merge partials -> nll ----------------
__global__ __launch_bounds__(256) void k_stageB(
    const float2* __restrict__ headP, const float2* __restrict__ tailP,
    const float2* __restrict__ stash, const int* __restrict__ target,
    const int* __restrict__ inv, float* __restrict__ out)
{
    const int wave = threadIdx.x >> 6, lane = threadIdx.x & 63;
    const int t = blockIdx.x * 4 + wave;
    const int tg = target[t];
    const int ci = (tg >= 5000) + (tg >= 15000) + (tg >= 30000);

    float m = -1e30f, s = 0.f;
    if (lane < HEAD_CHUNKS) { float2 p = headP[(size_t)t * HEAD_CHUNKS + lane]; m = p.x; s = p.y; }
    #pragma unroll
    for (int off = 1; off < 64; off <<= 1) {
        float m2 = __shfl_xor(m, off, 64);
        float s2 = __shfl_xor(s, off, 64);
        float M = fmaxf(m, m2);
        s = s * __expf(m - M) + s2 * __expf(m2 - M);
        m = M;
    }
    float2 st = stash[t];
    float nll = (m + __logf(s)) - st.x;

    if (ci) {
        const int nch_[4] = {0, 79, 118, 159};
        const int nch = nch_[ci];
        const int pos = inv[t];
        float m2 = -1e30f, s2 = 0.f;
        for (int c = lane; c < nch; c += 64) {
            float2 p = tailP[(size_t)pos * TAILP_STRIDE + c];
            float M = fmaxf(m2, p.x);
            s2 = s2 * __expf(m2 - M) + p.y * __expf(p.x - M);
            m2 = M;
        }
        #pragma unroll
        for (int off = 1; off < 64; off <<= 1) {
            float mm = __shfl_xor(m2, off, 64);
            float ss = __shfl_xor(s2, off, 64);
            float M = fmaxf(m2, mm);
            s2 = s2 * __expf(m2 - M) + ss * __expf(mm - M);
            m2 = M;
        }
        nll += (m2 + __logf(s2)) - st.y;
    }
    if (lane == 0) out[t] = nll;
}

extern "C" void kernel_launch(void* const* d_in, const int* in_sizes, int n_in,
                              void* d_out, int out_size, void* d_ws, size_t ws_size,
                              hipStream_t stream) {
    const float* hidden  = (const float*)d_in[0];
    const int*   targetp = (const int*)d_in[1];
    const float* weight  = (const float*)d_in[2];
    const float* biasp   = (const float*)d_in[3];
    const float* cweight = (const float*)d_in[4];
    const float* cbias   = (const float*)d_in[5];
    float* outp = (float*)d_out;

    char* ws = (char*)d_ws;
    unsigned short* wsW   = (unsigned short*)(ws);                 // 51,904,512 B
    float*          wsB   = (float*)(ws + 51904512);               //    202,752 B
    unsigned short* wsH   = (unsigned short*)(ws + 52107264);      //  4,194,304 B
    unsigned short* wsHc  = (unsigned short*)(ws + 56301568);      //  4,849,664 B
    float2*         headP = (float2*)(ws + 61151232);              //  1,310,720 B
    float2*         tailP = (float2*)(ws + 62461952);              //  6,062,080 B
    float2*         wsS   = (float2*)(ws + 68524032);              //     32,768 B
    int*            perm  = (int*)(ws + 68556800);                 //     18,944 B
    int*            inv   = (int*)(ws + 68575744);                 //     16,384 B
    int*            meta  = (int*)(ws + 68592128);                 //         64 B

    k_bucket<<<1, 256, 0, stream>>>(targetp, perm, inv, meta);
    k_convert<<<NROWS_PAD + NTOK + NTOKP, 128, 0, stream>>>(
        weight, biasp, cweight, cbias, hidden, perm, wsW, wsB, wsH, wsHc);
    k_stash<<<NTOK / 4, 256, 0, stream>>>(hidden, targetp, weight, biasp,
                                          cweight, cbias, wsS);
    k_gemm_all<<<12672, 256, 0, stream>>>(wsW, wsB, wsH, wsHc, headP, tailP, meta);
    k_stageB<<<NTOK / 4, 256, 0, stream>>>(headP, tailP, wsS, targetp, inv, outp);
}

// Round 7
// 238.966 us; speedup vs baseline: 1.8251x; 1.8251x over previous
//
#include <hip/hip_runtime.h>

// Adaptive softmax NLL — merged bf16-MFMA GEMM, BK=64, A-only LDS (34.8KB ->
// 4 blocks/CU), B read as pre-packed MFMA fragments straight from global (L2).
//
// Padded reordered weight (bf16) in ws (128-row chunks):
//   head : rows [0,5120)      = weight[0:5000] ++ cluster_weight ++ pad (40 chunks)
//   tail1: rows [5120,15232)  = weight[5000:15000]  ++ pad (79 chunks)
//   tail2: rows [15232,30336) = weight[15000:30000] ++ pad (118 chunks)
//   tail3: rows [30336,50688) = weight[30000:50257] ++ pad (159 chunks)
// Pad rows: w=0, bias=-1e30 (vanish in exp-weighted LSE merges).
// Packed H tile layout (128 tokens x 512 k = 128KB): elem16 = ke*128 + tok,
// ke = kt*8 + ks*4 + kg  (k = kt*64 + ks*32 + kg*8), one 16B frag per elem16.

#define D 512
#define NROWS_PAD 50688
#define NTOK 4096
#define NTOKP 4736
#define HEAD_CHUNKS 40
#define TAILP_STRIDE 160
#define HP_TILES 32
#define HCP_TILES 37

typedef __attribute__((ext_vector_type(8))) short short8;
typedef __attribute__((ext_vector_type(4))) float f32x4;

__device__ __forceinline__ unsigned short f2bf(float f) {
    unsigned int u = __float_as_uint(f);
    u += 0x7FFFu + ((u >> 16) & 1u);
    return (unsigned short)(u >> 16);
}

__device__ __forceinline__ void gload_lds16(const void* g, void* l) {
    __builtin_amdgcn_global_load_lds(
        (const __attribute__((address_space(1))) unsigned int*)g,
        (__attribute__((address_space(3))) unsigned int*)l, 16, 0, 0);
}

// ---------------- bucket tokens by cluster (deterministic counting sort) ----------------
__global__ __launch_bounds__(256) void k_bucket(
    const int* __restrict__ target, int* __restrict__ perm,
    int* __restrict__ inv, int* __restrict__ meta)
{
    __shared__ int cnt[256][4];
    __shared__ int basesh[256][4];
    __shared__ int sTot[4], sOff[4];
    const int th = threadIdx.x;
    for (int p = th; p < NTOKP; p += 256) perm[p] = -1;
    int lc[4] = {0, 0, 0, 0};
    #pragma unroll
    for (int i = 0; i < 16; ++i) {
        int tg = target[th * 16 + i];
        int c = (tg >= 5000) + (tg >= 15000) + (tg >= 30000);
        lc[c]++;
    }
    #pragma unroll
    for (int c = 0; c < 4; ++c) cnt[th][c] = lc[c];
    __syncthreads();
    if (th < 4) {
        int tot = 0;
        for (int i = 0; i < 256; ++i) tot += cnt[i][th];
        sTot[th] = tot;
    }
    __syncthreads();
    if (th == 0) {
        int b = 0;
        for (int c = 1; c < 4; ++c) { sOff[c] = b; b += ((sTot[c] + 127) >> 7) << 7; }
        meta[0] = sTot[1]; meta[1] = sTot[2]; meta[2] = sTot[3];
        meta[3] = sOff[1]; meta[4] = sOff[2]; meta[5] = sOff[3];
        meta[6] = (sTot[1] + 127) >> 7;
        meta[7] = (sTot[2] + 127) >> 7;
        meta[8] = (sTot[3] + 127) >> 7;
    }
    __syncthreads();
    if (th >= 1 && th < 4) {
        int run = sOff[th];
        for (int i = 0; i < 256; ++i) { basesh[i][th] = run; run += cnt[i][th]; }
    }
    __syncthreads();
    int run[4];
    #pragma unroll
    for (int c = 1; c < 4; ++c) run[c] = basesh[th][c];
    for (int i = 0; i < 16; ++i) {
        int t = th * 16 + i;
        int tg = target[t];
        int c = (tg >= 5000) + (tg >= 15000) + (tg >= 30000);
        if (c > 0) { int pos = run[c]++; perm[pos] = t; inv[t] = pos; }
        else inv[t] = -1;
    }
}

// ---------------- convert weight + pack hidden into fragment order ----------------
__global__ __launch_bounds__(128) void k_convert(
    const float* __restrict__ weight, const float* __restrict__ bias,
    const float* __restrict__ cweight, const float* __restrict__ cbias,
    const float* __restrict__ hidden, const int* __restrict__ perm,
    unsigned short* __restrict__ wsW, float* __restrict__ wsB,
    unsigned short* __restrict__ Hp, unsigned short* __restrict__ Hcp)
{
    const int r = blockIdx.x;
    const int i = threadIdx.x;   // 0..127
    if (r < NROWS_PAD) {
        const int pstart[4] = {0, 5120, 15232, 30336};
        const int plen[4]   = {5003, 10000, 15000, 20257};
        const int psrc[4]   = {0, 5000, 15000, 30000};
        int p = (r < 5120) ? 0 : (r < 15232) ? 1 : (r < 30336) ? 2 : 3;
        int o = r - pstart[p];
        const float* src = nullptr;
        float b = -1e30f;
        if (o < plen[p]) {
            if (p == 0 && o >= 5000) { src = cweight + (size_t)(o - 5000) * D; b = cbias[o - 5000]; }
            else { int sr = psrc[p] + o; src = weight + (size_t)sr * D; b = bias[sr]; }
        }
        float4 v = src ? ((const float4*)src)[i] : make_float4(0.f, 0.f, 0.f, 0.f);
        ushort4 u;
        u.x = f2bf(v.x); u.y = f2bf(v.y); u.z = f2bf(v.z); u.w = f2bf(v.w);
        ((ushort4*)(wsW + (size_t)r * D))[i] = u;
        if (i == 0) wsB[r] = b;
    } else {
        // packed-fragment hidden: one thread per 16B output (write-coalesced)
        int t = (r - NROWS_PAD) * 128 + i;          // 0 .. 565247
        int tau_all = t >> 13;                      // tile index, 0..68
        int e = t & 8191;
        int tok = e & 127;
        int ke = e >> 7;                            // kt*8 + ks*4 + kg
        int k0 = (ke >> 3) * 64 + ((ke >> 2) & 1) * 32 + (ke & 3) * 8;
        int gtok;
        unsigned short* dst;
        if (tau_all < HP_TILES) {
            gtok = tau_all * 128 + tok;
            dst = Hp + (size_t)t * 8;
        } else {
            int pos = (tau_all - HP_TILES) * 128 + tok;
            gtok = perm[pos];
            dst = Hcp + (size_t)(t - HP_TILES * 8192) * 8;
        }
        ushort4 u0 = {0, 0, 0, 0}, u1 = {0, 0, 0, 0};
        if (gtok >= 0) {
            const float4* src = (const float4*)(hidden + (size_t)gtok * D + k0);
            float4 a = src[0], b = src[1];
            u0.x = f2bf(a.x); u0.y = f2bf(a.y); u0.z = f2bf(a.z); u0.w = f2bf(a.w);
            u1.x = f2bf(b.x); u1.y = f2bf(b.y); u1.z = f2bf(b.z); u1.w = f2bf(b.w);
        }
        ((ushort4*)dst)[0] = u0;
        ((ushort4*)dst)[1] = u1;
    }
}

// ---------------- exact fp32 dots for the two needed logits ----------------
__global__ __launch_bounds__(256) void k_stash(
    const float* __restrict__ hidden, const int* __restrict__ target,
    const float* __restrict__ weight, const float* __restrict__ bias,
    const float* __restrict__ cweight, const float* __restrict__ cbias,
    float2* __restrict__ stash)
{
    const int wave = threadIdx.x >> 6, lane = threadIdx.x & 63;
    const int t = blockIdx.x * 4 + wave;
    const int tg = target[t];
    const int ci = (tg >= 5000) + (tg >= 15000) + (tg >= 30000);
    const float4* h = (const float4*)(hidden + (size_t)t * D);
    const float4* w = (const float4*)(weight + (size_t)tg * D);
    const float4* c = (const float4*)(cweight + (size_t)(ci ? 3 - ci : 0) * D);
    float dw = 0.f, dc = 0.f;
    #pragma unroll
    for (int u = 0; u < 2; ++u) {
        float4 hh = h[lane * 2 + u];
        float4 ww = w[lane * 2 + u];
        float4 cc = c[lane * 2 + u];
        dw += hh.x * ww.x + hh.y * ww.y + hh.z * ww.z + hh.w * ww.w;
        dc += hh.x * cc.x + hh.y * cc.y + hh.z * cc.z + hh.w * cc.w;
    }
    #pragma unroll
    for (int off = 1; off < 64; off <<= 1) {
        dw += __shfl_xor(dw, off, 64);
        dc += __shfl_xor(dc, off, 64);
    }
    if (lane == 0) {
        float head = ci ? dc + cbias[3 - ci] : dw + bias[tg];
        float tail = ci ? dw + bias[tg]      : 0.f;
        stash[t] = make_float2(head, tail);
    }
}

// ---------------- merged 128x128 GEMM (BK=64, A-only LDS) + per-chunk LSE ----------------
// 256 threads = 4 waves (2Mx2N). A staged via global_load_lds w/ XOR swizzle
// (R3-verified); B fragments loaded directly from packed global (coalesced 16B).
__global__ __launch_bounds__(256, 4) void k_gemm_all(
    const unsigned short* __restrict__ wsW, const float* __restrict__ wsB,
    const unsigned short* __restrict__ Hp, const unsigned short* __restrict__ Hcp,
    float2* __restrict__ headP, float2* __restrict__ tailP,
    const int* __restrict__ meta)
{
    // 12672 = 8 * 1584: give each XCD a contiguous chunk-major work range
    const int work = (blockIdx.x & 7) * 1584 + (blockIdx.x >> 3);
    int p, chunk, tau;
    if (work < 1280)      { p = 0; chunk = work >> 5;          tau = work & 31; }
    else if (work < 3808) { p = 1; chunk = (work - 1280) >> 5; tau = (work - 1280) & 31; }
    else if (work < 7584) { p = 2; chunk = (work - 3808) >> 5; tau = (work - 3808) & 31; }
    else                  { p = 3; chunk = (work - 7584) >> 5; tau = (work - 7584) & 31; }

    int tokBase = 0;
    const unsigned short* Hb;
    if (p == 0) {
        Hb = Hp + (size_t)tau * 65536;
    } else {
        if (tau >= meta[5 + p]) return;     // data-dependent token-tile count
        tokBase = meta[2 + p];
        Hb = Hcp + ((size_t)(tokBase >> 7) + tau) * 65536;
    }
    const int pstart_[4] = {0, 5120, 15232, 30336};
    const int rowBase = pstart_[p] + chunk * 128;

    const int tid = threadIdx.x;
    const int w = tid >> 6, lane = tid & 63;
    const int wm = w >> 1, wn = w & 1;
    const int lm = lane & 15, kg = lane >> 4;

    __shared__ unsigned short ldsA[2][128 * 64];    // 32 KB
    __shared__ float2 sred[2][128];                 //  2 KB

    const unsigned short* Wb = wsW + (size_t)rowBase * D;

    auto STAGE = [&](int buf, int kt) {
        #pragma unroll
        for (int j = 0; j < 4; ++j) {
            int e = w * 256 + j * 64 + lane;
            int r = e >> 3;
            int ck = (e & 7) ^ (r & 7);             // inverse-swizzled source chunk
            size_t go = (size_t)r * D + (size_t)kt * 64 + ck * 8;
            gload_lds16(Wb + go, &ldsA[buf][(w * 4 + j) * 512]);
        }
    };

    f32x4 acc[4][4];
    #pragma unroll
    for (int m = 0; m < 4; ++m)
        #pragma unroll
        for (int n = 0; n < 4; ++n) acc[m][n] = (f32x4){0.f, 0.f, 0.f, 0.f};

    const int bLane = kg * 1024 + (wn * 64 + lm) * 8;   // ushort offset, n-invariant
    const int xorv = (lane & 7) << 4;
    const int rowA = wm * 64 + lm;

    STAGE(0, 0);
    __syncthreads();

    int buf = 0;
    for (int s = 0; s < 8; ++s) {
        if (s < 7) STAGE(buf ^ 1, s + 1);
        #pragma unroll
        for (int ks = 0; ks < 2; ++ks) {
            const unsigned short* Bp = Hb + (s * 2 + ks) * 4096 + bLane;
            short8 bfr[4], af[4];
            #pragma unroll
            for (int n = 0; n < 4; ++n)
                bfr[n] = *(const short8*)(Bp + n * 128);
            const int koff = (ks * 64 + kg * 16) ^ xorv;
            #pragma unroll
            for (int m = 0; m < 4; ++m)
                af[m] = *(const short8*)((const char*)&ldsA[buf][0] + (rowA + m * 16) * 128 + koff);
            #pragma unroll
            for (int m = 0; m < 4; ++m)
                #pragma unroll
                for (int n = 0; n < 4; ++n)
                    acc[m][n] = __builtin_amdgcn_mfma_f32_16x16x32_bf16(af[m], bfr[n], acc[m][n], 0, 0, 0);
        }
        __syncthreads();
        buf ^= 1;
    }

    // epilogue: bias + per-token LSE over this chunk's 128 rows
    f32x4 bb[4];
    #pragma unroll
    for (int m = 0; m < 4; ++m)
        bb[m] = *(const f32x4*)(wsB + rowBase + wm * 64 + m * 16 + kg * 4);

    #pragma unroll
    for (int n = 0; n < 4; ++n) {
        float mval = -1e30f;
        #pragma unroll
        for (int m = 0; m < 4; ++m)
            #pragma unroll
            for (int j = 0; j < 4; ++j) {
                acc[m][n][j] += bb[m][j];
                mval = fmaxf(mval, acc[m][n][j]);
            }
        float sval = 0.f;
        #pragma unroll
        for (int m = 0; m < 4; ++m)
            #pragma unroll
            for (int j = 0; j < 4; ++j)
                sval += __expf(acc[m][n][j] - mval);
        #pragma unroll
        for (int off = 16; off < 64; off <<= 1) {
            float m2 = __shfl_xor(mval, off, 64);
            float s2 = __shfl_xor(sval, off, 64);
            float M = fmaxf(mval, m2);
            sval = sval * __expf(mval - M) + s2 * __expf(m2 - M);
            mval = M;
        }
        if (lane < 16)
            sred[wm][wn * 64 + n * 16 + lane] = make_float2(mval, sval);
    }
    __syncthreads();
    if (tid < 128) {
        float2 p0 = sred[0][tid], p1 = sred[1][tid];
        float M = fmaxf(p0.x, p1.x);
        float S = p0.y * __expf(p0.x - M) + p1.y * __expf(p1.x - M);
        if (p == 0)
            headP[(size_t)(tau * 128 + tid) * HEAD_CHUNKS + chunk] = make_float2(M, S);
        else
            tailP[(size_t)(tokBase + tau * 128 + tid) * TAILP_STRIDE + chunk] = make_float2(M, S);
    }
}

// ---------------- merge partials -> nll ----------------
__global__ __launch_bounds__(256) void k_stageB(
    const float2* __restrict__ headP, const float2* __restrict__ tailP,
    const float2* __restrict__ stash, const int* __restrict__ target,
    const int* __restrict__ inv, float* __restrict__ out)
{
    const int wave = threadIdx.x >> 6, lane = threadIdx.x & 63;
    const int t = blockIdx.x * 4 + wave;
    const int tg = target[t];
    const int ci = (tg >= 5000) + (tg >= 15000) + (tg >= 30000);

    float m = -1e30f, s = 0.f;
    if (lane < HEAD_CHUNKS) { float2 p = headP[(size_t)t * HEAD_CHUNKS + lane]; m = p.x; s = p.y; }
    #pragma unroll
    for (int off = 1; off < 64; off <<= 1) {
        float m2 = __shfl_xor(m, off, 64);
        float s2 = __shfl_xor(s, off, 64);
        float M = fmaxf(m, m2);
        s = s * __expf(m - M) + s2 * __expf(m2 - M);
        m = M;
    }
    float2 st = stash[t];
    float nll = (m + __logf(s)) - st.x;

    if (ci) {
        const int nch_[4] = {0, 79, 118, 159};
        const int nch = nch_[ci];
        const int pos = inv[t];
        float m2 = -1e30f, s2 = 0.f;
        for (int c = lane; c < nch; c += 64) {
            float2 p = tailP[(size_t)pos * TAILP_STRIDE + c];
            float M = fmaxf(m2, p.x);
            s2 = s2 * __expf(m2 - M) + p.y * __expf(p.x - M);
            m2 = M;
        }
        #pragma unroll
        for (int off = 1; off < 64; off <<= 1) {
            float mm = __shfl_xor(m2, off, 64);
            float ss = __shfl_xor(s2, off, 64);
            float M = fmaxf(m2, mm);
            s2 = s2 * __expf(m2 - M) + ss * __expf(mm - M);
            m2 = M;
        }
        nll += (m2 + __logf(s2)) - st.y;
    }
    if (lane == 0) out[t] = nll;
}

extern "C" void kernel_launch(void* const* d_in, const int* in_sizes, int n_in,
                              void* d_out, int out_size, void* d_ws, size_t ws_size,
                              hipStream_t stream) {
    const float* hidden  = (const float*)d_in[0];
    const int*   targetp = (const int*)d_in[1];
    const float* weight  = (const float*)d_in[2];
    const float* biasp   = (const float*)d_in[3];
    const float* cweight = (const float*)d_in[4];
    const float* cbias   = (const float*)d_in[5];
    float* outp = (float*)d_out;

    char* ws = (char*)d_ws;
    unsigned short* wsW   = (unsigned short*)(ws);                 // 51,904,512 B
    float*          wsB   = (float*)(ws + 51904512);               //    202,752 B
    unsigned short* Hp    = (unsigned short*)(ws + 52107264);      //  4,194,304 B (32 tiles)
    unsigned short* Hcp   = (unsigned short*)(ws + 56301568);      //  4,849,664 B (37 tiles)
    float2*         headP = (float2*)(ws + 61151232);              //  1,310,720 B
    float2*         tailP = (float2*)(ws + 62461952);              //  6,062,080 B
    float2*         wsS   = (float2*)(ws + 68524032);              //     32,768 B
    int*            perm  = (int*)(ws + 68556800);                 //     18,944 B
    int*            inv   = (int*)(ws + 68575744);                 //     16,384 B
    int*            meta  = (int*)(ws + 68592128);                 //         64 B

    k_bucket<<<1, 256, 0, stream>>>(targetp, perm, inv, meta);
    k_convert<<<NROWS_PAD + 4416, 128, 0, stream>>>(
        weight, biasp, cweight, cbias, hidden, perm, wsW, wsB, Hp, Hcp);
    k_stash<<<NTOK / 4, 256, 0, stream>>>(hidden, targetp, weight, biasp,
                                          cweight, cbias, wsS);
    k_gemm_all<<<12672, 256, 0, stream>>>(wsW, wsB, Hp, Hcp, headP, tailP, meta);
    k_stageB<<<NTOK / 4, 256, 0, stream>>>(headP, tailP, wsS, targetp, inv, outp);
}